// Round 7
// baseline (441.635 us; speedup 1.0000x reference)
//
#include <hip/hip_runtime.h>

#define DID 128
#define NCLS 8
#define NPB 512        // nodes per bucket (power of 2)
#define NPB_SHIFT 9
#define NBLK 512       // blocks in edge-partition kernels
#define CAP 12288      // col staging capacity per bucket
#define PCHUNK 64      // pooling chunks per graph

typedef __attribute__((ext_vector_type(8))) short bf16x8;
typedef __attribute__((ext_vector_type(4))) float f32x4;
typedef __attribute__((ext_vector_type(8))) unsigned short u16x8;

static __device__ __forceinline__ unsigned short f2bf(float f) {
  union { float f; unsigned int u; } x;
  x.f = f;
  unsigned int r = (x.u + 0x7fffu + ((x.u >> 16) & 1u)) >> 16;  // RNE
  return (unsigned short)r;
}
static __device__ __forceinline__ float bfhi(unsigned int v) {
  union { unsigned int u; float f; } x;
  x.u = v & 0xffff0000u;
  return x.f;
}
static __device__ __forceinline__ float bflo(unsigned int v) {
  union { unsigned int u; float f; } x;
  x.u = v << 16;
  return x.f;
}
static __device__ __forceinline__ int lowerb(const int* __restrict__ a, int n,
                                             int key) {
  int lo = 0, hi = n;
  while (lo < hi) {
    int m = (lo + hi) >> 1;
    if (a[m] < key) lo = m + 1;
    else hi = m;
  }
  return lo;
}

// --------------------------------------------- fused prep kernel (4 phases)
// [0,ncvt): h fp32->bf16 | [ncvt,+256): W pack | [+NBLK): dst bucket hist |
// last block: zero gsum
__global__ __launch_bounds__(256) void k_prep(
    const float* __restrict__ h, unsigned short* __restrict__ hb, int total8,
    int ncvt, const float* __restrict__ W0, const float* __restrict__ W1,
    const float* __restrict__ W2, const float* __restrict__ W3,
    unsigned short* __restrict__ P0, unsigned short* __restrict__ P1,
    unsigned short* __restrict__ P2, unsigned short* __restrict__ P3,
    const int* __restrict__ dst, int* __restrict__ hist, int E, int nbuk,
    float* __restrict__ gsum, int ngsum) {
  __shared__ int c[256];
  int bid = blockIdx.x;
  int tid = threadIdx.x;
  if (bid < ncvt) {  // ---- h -> bf16
    int i = bid * 256 + tid;
    if (i >= total8) return;
    const float4* h4 = (const float4*)h;
    float4 a = h4[(size_t)i * 2];
    float4 b = h4[(size_t)i * 2 + 1];
    u16x8 o;
    o[0] = f2bf(a.x); o[1] = f2bf(a.y); o[2] = f2bf(a.z); o[3] = f2bf(a.w);
    o[4] = f2bf(b.x); o[5] = f2bf(b.y); o[6] = f2bf(b.z); o[7] = f2bf(b.w);
    *(u16x8*)(hb + (size_t)i * 8) = o;
  } else if (bid < ncvt + 256) {  // ---- pack 4 weight matrices
    int gid = (bid - ncvt) * 256 + tid;  // 0..65535
    int m = gid >> 14;
    int idx = gid & 16383;
    int j = idx & 7;
    int l = (idx >> 3) & 63;
    int kf = (idx >> 9) & 3;
    int ct = idx >> 11;
    int colc = ct * 16 + (l & 15);
    int k = kf * 32 + (l >> 4) * 8 + j;
    const float* W = (m == 0) ? W0 : (m == 1) ? W1 : (m == 2) ? W2 : W3;
    unsigned short* P = (m == 0) ? P0 : (m == 1) ? P1 : (m == 2) ? P2 : P3;
    P[idx] = f2bf(W[k * 128 + colc]);
  } else if (bid < ncvt + 256 + NBLK) {  // ---- bucket histogram
    int b = bid - ncvt - 256;
    for (int i = tid; i < nbuk; i += 256) c[i] = 0;
    __syncthreads();
    int epb = (E + NBLK - 1) / NBLK;
    int e0 = b * epb;
    int e1 = min(E, e0 + epb);
    for (int e = e0 + tid; e < e1; e += 256)
      atomicAdd(&c[dst[e] >> NPB_SHIFT], 1);
    __syncthreads();
    for (int i = tid; i < nbuk; i += 256)
      hist[(size_t)i * NBLK + b] = c[i];
  } else {  // ---- zero gsum
    for (int i = tid; i < ngsum; i += 256) gsum[i] = 0.f;
  }
}

// generic exclusive scan chain (1024 elems / 256-thr block)
__global__ void k_scan1(const int* __restrict__ deg, int* __restrict__ rp,
                        int* __restrict__ part, int n) {
  __shared__ int sd[256];
  int t = threadIdx.x;
  int base = blockIdx.x * 1024 + t * 4;
  int v0 = (base + 0 < n) ? deg[base + 0] : 0;
  int v1 = (base + 1 < n) ? deg[base + 1] : 0;
  int v2 = (base + 2 < n) ? deg[base + 2] : 0;
  int v3 = (base + 3 < n) ? deg[base + 3] : 0;
  int ts = v0 + v1 + v2 + v3;
  sd[t] = ts;
  __syncthreads();
  for (int off = 1; off < 256; off <<= 1) {
    int x = 0;
    if (t >= off) x = sd[t - off];
    __syncthreads();
    if (t >= off) sd[t] += x;
    __syncthreads();
  }
  int excl = sd[t] - ts;
  if (base + 0 < n) rp[base + 0] = excl;
  if (base + 1 < n) rp[base + 1] = excl + v0;
  if (base + 2 < n) rp[base + 2] = excl + v0 + v1;
  if (base + 3 < n) rp[base + 3] = excl + v0 + v1 + v2;
  if (t == 255) part[blockIdx.x] = sd[255];
}

__global__ void k_scan2(int* __restrict__ part, int nblk) {
  __shared__ int sd[1024];
  int t = threadIdx.x;
  int v = (t < nblk) ? part[t] : 0;
  sd[t] = v;
  __syncthreads();
  for (int off = 1; off < 1024; off <<= 1) {
    int x = 0;
    if (t >= off) x = sd[t - off];
    __syncthreads();
    if (t >= off) sd[t] += x;
    __syncthreads();
  }
  if (t < nblk) part[t] = sd[t] - v;
}

__global__ void k_scan3(int* __restrict__ rp, const int* __restrict__ part,
                        int n, int E) {
  int t = threadIdx.x;
  int add = part[blockIdx.x];
  int base = blockIdx.x * 1024 + t * 4;
#pragma unroll
  for (int i = 0; i < 4; ++i)
    if (base + i < n) rp[base + i] += add;
  if (blockIdx.x == 0 && t == 0) rp[n] = E;
}

// -------------------------------------------- bucketed CSR: pass A scatter
__global__ __launch_bounds__(256) void kB_scat(const int* __restrict__ src,
                                               const int* __restrict__ dst,
                                               const int* __restrict__ off,
                                               unsigned long long* __restrict__ pairs,
                                               int E, int nbuk) {
  __shared__ int cur[256];
  int tid = threadIdx.x;
  for (int i = tid; i < nbuk; i += 256)
    cur[i] = off[(size_t)i * NBLK + blockIdx.x];
  __syncthreads();
  int epb = (E + NBLK - 1) / NBLK;
  int e0 = blockIdx.x * epb;
  int e1 = min(E, e0 + epb);
  for (int e = e0 + tid; e < e1; e += 256) {
    int s = src[e];
    int d = dst[e];
    int p = atomicAdd(&cur[d >> NPB_SHIFT], 1);
    pairs[p] = ((unsigned long long)(unsigned)d << 32) | (unsigned)s;
  }
}

// ---------------------------------------------- bucketed CSR: pass B build
__global__ __launch_bounds__(512) void kB_build(
    const unsigned long long* __restrict__ pairs, const int* __restrict__ off,
    int* __restrict__ rp, int* __restrict__ col, int N, int nbuk, int E) {
  __shared__ int cnt[NPB];
  __shared__ int exc[NPB];
  __shared__ int colstage[CAP];
  int tid = threadIdx.x;
  int b = blockIdx.x;
  int eb = off[(size_t)b * NBLK];
  int ee = off[(size_t)(b + 1) * NBLK];
  int m = ee - eb;

  cnt[tid] = 0;
  __syncthreads();
  for (int i = eb + tid; i < ee; i += NPB) {
    int d = (int)(pairs[i] >> 32);
    atomicAdd(&cnt[d & (NPB - 1)], 1);
  }
  __syncthreads();
  exc[tid] = cnt[tid];
  __syncthreads();
  for (int o = 1; o < NPB; o <<= 1) {
    int v = (tid >= o) ? exc[tid - o] : 0;
    __syncthreads();
    exc[tid] += v;
    __syncthreads();
  }
  int myexc = exc[tid] - cnt[tid];
  int node = b * NPB + tid;
  if (node < N) rp[node] = eb + myexc;
  if (b == nbuk - 1 && tid == 0) rp[N] = E;
  __syncthreads();
  cnt[tid] = myexc;  // reuse as cursor
  __syncthreads();
  if (m <= CAP) {
    for (int i = eb + tid; i < ee; i += NPB) {
      unsigned long long pr = pairs[i];
      int d = (int)(pr >> 32);
      int s = (int)(pr & 0xffffffffu);
      int p = atomicAdd(&cnt[d & (NPB - 1)], 1);
      colstage[p] = s;
    }
    __syncthreads();
    for (int i = tid; i < m; i += NPB) col[eb + i] = colstage[i];
  } else {
    for (int i = eb + tid; i < ee; i += NPB) {
      unsigned long long pr = pairs[i];
      int d = (int)(pr >> 32);
      int s = (int)(pr & 0xffffffffu);
      int p = atomicAdd(&cnt[d & (NPB - 1)], 1);
      col[eb + p] = s;
    }
  }
}

// ------------------------------------------------------- fused MFMA GEMM
__global__ __launch_bounds__(256, 2) void k_gemm2(
    const unsigned short* __restrict__ hb, const unsigned short* __restrict__ WpS,
    const unsigned short* __restrict__ WpN, float* __restrict__ z,
    unsigned short* __restrict__ yb, int n) {
  const int l = threadIdx.x & 63;
  const int w = threadIdx.x >> 6;
  const int rowW = blockIdx.x * 128 + w * 32;
  const int cl = l & 15;
  const int cg = l >> 4;

  bf16x8 A[2][4];
#pragma unroll
  for (int rt = 0; rt < 2; ++rt) {
    int row = rowW + rt * 16 + cl;
#pragma unroll
    for (int kf = 0; kf < 4; ++kf) {
      if (row < n)
        A[rt][kf] = *(const bf16x8*)(hb + (size_t)row * 128 + kf * 32 + cg * 8);
      else
        A[rt][kf] = (bf16x8){0, 0, 0, 0, 0, 0, 0, 0};
    }
  }

  f32x4 accS[2][8], accN[2][8];
#pragma unroll
  for (int rt = 0; rt < 2; ++rt)
#pragma unroll
    for (int ct = 0; ct < 8; ++ct) {
      accS[rt][ct] = (f32x4){0.f, 0.f, 0.f, 0.f};
      accN[rt][ct] = (f32x4){0.f, 0.f, 0.f, 0.f};
    }

#pragma unroll
  for (int ct = 0; ct < 8; ++ct) {
    bf16x8 BS[4], BN[4];
#pragma unroll
    for (int kf = 0; kf < 4; ++kf) {
      BS[kf] = *(const bf16x8*)(WpS + ((ct * 4 + kf) * 64 + l) * 8);
      BN[kf] = *(const bf16x8*)(WpN + ((ct * 4 + kf) * 64 + l) * 8);
    }
#pragma unroll
    for (int rt = 0; rt < 2; ++rt)
#pragma unroll
      for (int kf = 0; kf < 4; ++kf) {
        accS[rt][ct] =
            __builtin_amdgcn_mfma_f32_16x16x32_bf16(A[rt][kf], BS[kf], accS[rt][ct], 0, 0, 0);
        accN[rt][ct] =
            __builtin_amdgcn_mfma_f32_16x16x32_bf16(A[rt][kf], BN[kf], accN[rt][ct], 0, 0, 0);
      }
  }

#pragma unroll
  for (int rt = 0; rt < 2; ++rt)
#pragma unroll
    for (int ct = 0; ct < 8; ++ct) {
#pragma unroll
      for (int r = 0; r < 4; ++r) {
        int row = rowW + rt * 16 + cg * 4 + r;
        if (row < n) {
          int colc = ct * 16 + cl;
          z[(size_t)row * 128 + colc] = accS[rt][ct][r];
          yb[(size_t)row * 128 + colc] = f2bf(accN[rt][ct][r]);
        }
      }
    }
}

// ------------------------------------------------- aggregation (pull, fused)
// 32-lane row groups: each lane loads uint2 (4 bf16 dims), one vmem
// instruction covers 2 edges -> 16 edges in flight at 8-deep unroll.
// Guarded tail block keeps full MLP on deg<16 nodes (exec-masked, no waste).
template <int OUTMODE>
__global__ __launch_bounds__(256, 4) void k_aggr2(
    const unsigned int* __restrict__ Y, const float* Z,
    const int* __restrict__ rp, const int* __restrict__ col,
    const float* __restrict__ bias, void* outp, int n) {
  int wid = (blockIdx.x * 256 + threadIdx.x) >> 6;
  int lane = threadIdx.x & 63;
  if (wid >= n) return;
  int half = lane >> 5;  // which edge of the pair
  int hl = lane & 31;    // uint2 slot within the 256B row
  const uint2* __restrict__ Y2 = (const uint2*)Y;
  int s = rp[wid], e = rp[wid + 1];
  float a0 = 0.f, a1 = 0.f, a2 = 0.f, a3 = 0.f;
  int i = s;
  for (; i + 16 <= e; i += 16) {
#pragma unroll
    for (int k = 0; k < 8; ++k) {
      int c = col[i + 2 * k + half];
      uint2 v = Y2[(size_t)c * 32 + hl];
      a0 += bflo(v.x); a1 += bfhi(v.x);
      a2 += bflo(v.y); a3 += bfhi(v.y);
    }
  }
  if (i < e) {
#pragma unroll
    for (int k = 0; k < 8; ++k) {
      int idx = i + 2 * k + half;
      if (idx < e) {
        int c = col[idx];
        uint2 v = Y2[(size_t)c * 32 + hl];
        a0 += bflo(v.x); a1 += bfhi(v.x);
        a2 += bflo(v.y); a3 += bfhi(v.y);
      }
    }
  }
  // combine the two half-waves
  a0 += __shfl_xor(a0, 32);
  a1 += __shfl_xor(a1, 32);
  a2 += __shfl_xor(a2, 32);
  a3 += __shfl_xor(a3, 32);
  int deg = e - s;
  float scale = 1.0f / (float)(deg > 1 ? deg : 1);
  if (half == 0) {
    float4 zv = ((const float4*)Z)[(size_t)wid * 32 + hl];
    float4 bb = ((const float4*)bias)[hl];
    float o0 = zv.x + a0 * scale + bb.x;
    float o1 = zv.y + a1 * scale + bb.y;
    float o2 = zv.z + a2 * scale + bb.z;
    float o3 = zv.w + a3 * scale + bb.w;
    if (OUTMODE == 1) {
      o0 = fmaxf(o0, 0.f); o1 = fmaxf(o1, 0.f);
      o2 = fmaxf(o2, 0.f); o3 = fmaxf(o3, 0.f);
      uint2 p;
      p.x = (unsigned)f2bf(o0) | ((unsigned)f2bf(o1) << 16);
      p.y = (unsigned)f2bf(o2) | ((unsigned)f2bf(o3) << 16);
      ((uint2*)outp)[(size_t)wid * 32 + hl] = p;
    } else {
      ((float4*)outp)[(size_t)wid * 32 + hl] = make_float4(o0, o1, o2, o3);
    }
  }
}

// ---------------------------------------------------------------- pooling
// NG*PCHUNK blocks x 256 thr; graph bounds via inline binary search.
__global__ __launch_bounds__(256) void k_pool(const float* __restrict__ H2,
                                              const int* __restrict__ gids,
                                              float* __restrict__ gsum, int N) {
  int g = blockIdx.x / PCHUNK;
  int c = blockIdx.x % PCHUNK;
  int t = threadIdx.x;
  int s = lowerb(gids, N, g);
  int e = lowerb(gids, N, g + 1);
  int cnt = e - s;
  int per = (cnt + PCHUNK - 1) / PCHUNK;
  int rs = s + c * per;
  int re = rs + per < e ? rs + per : e;
  if (rs >= re) return;  // uniform per block
  int rslot = t >> 5;    // 0..7
  int d4 = t & 31;       // float4 index within row
  const float4* H4 = (const float4*)H2;
  float4 acc = make_float4(0.f, 0.f, 0.f, 0.f);
  for (int r = rs + rslot; r < re; r += 8) {
    float4 v = H4[(size_t)r * 32 + d4];
    acc.x += v.x; acc.y += v.y; acc.z += v.z; acc.w += v.w;
  }
  __shared__ float4 sacc[256];
  sacc[t] = acc;
  __syncthreads();
#pragma unroll
  for (int o = 4; o >= 1; o >>= 1) {
    if (rslot < o) {
      float4 a = sacc[t];
      float4 b = sacc[t + o * 32];
      a.x += b.x; a.y += b.y; a.z += b.z; a.w += b.w;
      sacc[t] = a;
    }
    __syncthreads();
  }
  if (t < 32) {
    float4 a = sacc[t];
    atomicAdd(&gsum[g * DID + t * 4 + 0], a.x);
    atomicAdd(&gsum[g * DID + t * 4 + 1], a.y);
    atomicAdd(&gsum[g * DID + t * 4 + 2], a.z);
    atomicAdd(&gsum[g * DID + t * 4 + 3], a.w);
  }
}

__global__ void k_head(const float* __restrict__ gsum,
                       const float* __restrict__ perm,
                       const float* __restrict__ Wc,
                       const float* __restrict__ bc,
                       const int* __restrict__ gids, float* __restrict__ out,
                       int N, int NG) {
  int t = threadIdx.x;
  if (t >= NG * NCLS) return;
  int g = t >> 3, c = t & 7;
  int cnt = lowerb(gids, N, g + 1) - lowerb(gids, N, g);
  float inv = 1.0f / (float)(cnt > 1 ? cnt : 1);
  float acc = bc[c];
#pragma unroll 4
  for (int k = 0; k < DID; ++k)
    acc += gsum[g * DID + k] * inv * Wc[k * NCLS + c];
#pragma unroll 4
  for (int k = 0; k < DID; ++k)
    acc += perm[g * DID + k] * Wc[(DID + k) * NCLS + c];
  out[g * NCLS + c] = acc;
}

// ---------------------------------------------------------------- launch
extern "C" void kernel_launch(void* const* d_in, const int* in_sizes, int n_in,
                              void* d_out, int out_size, void* d_ws,
                              size_t ws_size, hipStream_t stream) {
  const float* h = (const float*)d_in[0];
  const float* perm = (const float*)d_in[1];
  const int* src = (const int*)d_in[2];
  const int* dst = (const int*)d_in[3];
  const int* gids = (const int*)d_in[4];
  const float* W1s = (const float*)d_in[5];
  const float* W1n = (const float*)d_in[6];
  const float* b1 = (const float*)d_in[7];
  const float* W2s = (const float*)d_in[8];
  const float* W2n = (const float*)d_in[9];
  const float* b2 = (const float*)d_in[10];
  const float* Wc = (const float*)d_in[11];
  const float* bc = (const float*)d_in[12];
  float* out = (float*)d_out;

  const int N = in_sizes[0] / DID;
  const int E = in_sizes[2];
  const int NG = in_sizes[1] / DID;
  const int nbuk = (N + NPB - 1) >> NPB_SHIFT;
  const int nscan = nbuk * NBLK;

  char* w = (char*)d_ws;
  size_t off_ = 0;
  auto alloc = [&](size_t bytes) -> void* {
    off_ = (off_ + 511) & ~(size_t)511;
    void* p = w + off_;
    off_ += bytes;
    return p;
  };
  float* gsum = (float*)alloc((size_t)NG * DID * 4);
  int* hist = (int*)alloc((size_t)nscan * 4);
  int* boff = (int*)alloc((size_t)(nscan + 1) * 4);
  int* part = (int*)alloc(1024 * 4);
  int* rp = (int*)alloc((size_t)(N + 1) * 4);
  int* col = (int*)alloc((size_t)E * 4);
  unsigned long long* pairs = (unsigned long long*)alloc((size_t)E * 8);
  unsigned short* hb = (unsigned short*)alloc((size_t)N * DID * 2);
  unsigned short* yb = (unsigned short*)alloc((size_t)N * DID * 2);
  float* z = (float*)alloc((size_t)N * DID * 4);
  unsigned short* Wp1s = (unsigned short*)alloc(128 * 128 * 2);
  unsigned short* Wp1n = (unsigned short*)alloc(128 * 128 * 2);
  unsigned short* Wp2s = (unsigned short*)alloc(128 * 128 * 2);
  unsigned short* Wp2n = (unsigned short*)alloc(128 * 128 * 2);

  const int nchunk = (nscan + 1023) / 1024;
  const int ngb = (N + 127) / 128;
  const int nagg = (N + 3) / 4;
  const int total8 = N * DID / 8;
  const int ncvt = (total8 + 255) / 256;

  // fused prep: h->bf16, weight pack, bucket hist, gsum zero
  k_prep<<<ncvt + 256 + NBLK + 1, 256, 0, stream>>>(
      h, hb, total8, ncvt, W1s, W1n, W2s, W2n, Wp1s, Wp1n, Wp2s, Wp2n, dst,
      hist, E, nbuk, gsum, NG * DID);

  // bucketed CSR by dst
  k_scan1<<<nchunk, 256, 0, stream>>>(hist, boff, part, nscan);
  k_scan2<<<1, 1024, 0, stream>>>(part, nchunk);
  k_scan3<<<nchunk, 256, 0, stream>>>(boff, part, nscan, E);
  kB_scat<<<NBLK, 256, 0, stream>>>(src, dst, boff, pairs, E, nbuk);
  kB_build<<<nbuk, NPB, 0, stream>>>(pairs, boff, rp, col, N, nbuk, E);

  // layer 1: z=h@W1s (f32), yb=h@W1n (bf16); aggr -> h1 bf16 (into hb)
  k_gemm2<<<ngb, 256, 0, stream>>>(hb, Wp1s, Wp1n, z, yb, N);
  k_aggr2<1><<<nagg, 256, 0, stream>>>((const unsigned int*)yb, z, rp, col, b1,
                                       (void*)hb, N);

  // layer 2: z=h1@W2s, yb=h1@W2n; aggr -> h2 fp32 (in-place in z)
  k_gemm2<<<ngb, 256, 0, stream>>>(hb, Wp2s, Wp2n, z, yb, N);
  k_aggr2<0><<<nagg, 256, 0, stream>>>((const unsigned int*)yb, z, rp, col, b2,
                                       (void*)z, N);

  // readout
  k_pool<<<NG * PCHUNK, 256, 0, stream>>>(z, gids, gsum, N);
  k_head<<<1, 512, 0, stream>>>(gsum, perm, Wc, bc, gids, out, N, NG);
}

// Round 8
// 420.954 us; speedup vs baseline: 1.0491x; 1.0491x over previous
//
#include <hip/hip_runtime.h>

#define DID 128
#define NCLS 8
#define NPB 512        // nodes per bucket (power of 2)
#define NPB_SHIFT 9
#define NBLK 256       // blocks in edge-partition kernels
#define CAP 12288      // col staging capacity per bucket
#define PCHUNK 64      // pooling chunks per graph

typedef __attribute__((ext_vector_type(8))) short bf16x8;
typedef __attribute__((ext_vector_type(4))) float f32x4;
typedef __attribute__((ext_vector_type(8))) unsigned short u16x8;

static __device__ __forceinline__ unsigned short f2bf(float f) {
  union { float f; unsigned int u; } x;
  x.f = f;
  unsigned int r = (x.u + 0x7fffu + ((x.u >> 16) & 1u)) >> 16;  // RNE
  return (unsigned short)r;
}
static __device__ __forceinline__ float bfhi(unsigned int v) {
  union { unsigned int u; float f; } x;
  x.u = v & 0xffff0000u;
  return x.f;
}
static __device__ __forceinline__ float bflo(unsigned int v) {
  union { unsigned int u; float f; } x;
  x.u = v << 16;
  return x.f;
}
static __device__ __forceinline__ int lowerb(const int* __restrict__ a, int n,
                                             int key) {
  int lo = 0, hi = n;
  while (lo < hi) {
    int m = (lo + hi) >> 1;
    if (a[m] < key) lo = m + 1;
    else hi = m;
  }
  return lo;
}

// --------------------------------------------- fused prep kernel (4 phases)
__global__ __launch_bounds__(256) void k_prep(
    const float* __restrict__ h, unsigned short* __restrict__ hb, int total8,
    int ncvt, const float* __restrict__ W0, const float* __restrict__ W1,
    const float* __restrict__ W2, const float* __restrict__ W3,
    unsigned short* __restrict__ P0, unsigned short* __restrict__ P1,
    unsigned short* __restrict__ P2, unsigned short* __restrict__ P3,
    const int* __restrict__ dst, int* __restrict__ hist, int E, int nbuk,
    float* __restrict__ gsum, int ngsum) {
  __shared__ int c[256];
  int bid = blockIdx.x;
  int tid = threadIdx.x;
  if (bid < ncvt) {  // ---- h -> bf16
    int i = bid * 256 + tid;
    if (i >= total8) return;
    const float4* h4 = (const float4*)h;
    float4 a = h4[(size_t)i * 2];
    float4 b = h4[(size_t)i * 2 + 1];
    u16x8 o;
    o[0] = f2bf(a.x); o[1] = f2bf(a.y); o[2] = f2bf(a.z); o[3] = f2bf(a.w);
    o[4] = f2bf(b.x); o[5] = f2bf(b.y); o[6] = f2bf(b.z); o[7] = f2bf(b.w);
    *(u16x8*)(hb + (size_t)i * 8) = o;
  } else if (bid < ncvt + 256) {  // ---- pack 4 weight matrices
    int gid = (bid - ncvt) * 256 + tid;  // 0..65535
    int m = gid >> 14;
    int idx = gid & 16383;
    int j = idx & 7;
    int l = (idx >> 3) & 63;
    int kf = (idx >> 9) & 3;
    int ct = idx >> 11;
    int colc = ct * 16 + (l & 15);
    int k = kf * 32 + (l >> 4) * 8 + j;
    const float* W = (m == 0) ? W0 : (m == 1) ? W1 : (m == 2) ? W2 : W3;
    unsigned short* P = (m == 0) ? P0 : (m == 1) ? P1 : (m == 2) ? P2 : P3;
    P[idx] = f2bf(W[k * 128 + colc]);
  } else if (bid < ncvt + 256 + NBLK) {  // ---- bucket histogram
    int b = bid - ncvt - 256;
    for (int i = tid; i < nbuk; i += 256) c[i] = 0;
    __syncthreads();
    int epb = (E + NBLK - 1) / NBLK;
    int e0 = b * epb;
    int e1 = min(E, e0 + epb);
    for (int e = e0 + tid; e < e1; e += 256)
      atomicAdd(&c[dst[e] >> NPB_SHIFT], 1);
    __syncthreads();
    for (int i = tid; i < nbuk; i += 256)
      hist[(size_t)i * NBLK + b] = c[i];
  } else {  // ---- zero gsum
    for (int i = tid; i < ngsum; i += 256) gsum[i] = 0.f;
  }
}

// generic exclusive scan chain (1024 elems / 256-thr block)
__global__ void k_scan1(const int* __restrict__ deg, int* __restrict__ rp,
                        int* __restrict__ part, int n) {
  __shared__ int sd[256];
  int t = threadIdx.x;
  int base = blockIdx.x * 1024 + t * 4;
  int v0 = (base + 0 < n) ? deg[base + 0] : 0;
  int v1 = (base + 1 < n) ? deg[base + 1] : 0;
  int v2 = (base + 2 < n) ? deg[base + 2] : 0;
  int v3 = (base + 3 < n) ? deg[base + 3] : 0;
  int ts = v0 + v1 + v2 + v3;
  sd[t] = ts;
  __syncthreads();
  for (int off = 1; off < 256; off <<= 1) {
    int x = 0;
    if (t >= off) x = sd[t - off];
    __syncthreads();
    if (t >= off) sd[t] += x;
    __syncthreads();
  }
  int excl = sd[t] - ts;
  if (base + 0 < n) rp[base + 0] = excl;
  if (base + 1 < n) rp[base + 1] = excl + v0;
  if (base + 2 < n) rp[base + 2] = excl + v0 + v1;
  if (base + 3 < n) rp[base + 3] = excl + v0 + v1 + v2;
  if (t == 255) part[blockIdx.x] = sd[255];
}

__global__ void k_scan2(int* __restrict__ part, int nblk) {
  __shared__ int sd[1024];
  int t = threadIdx.x;
  int v = (t < nblk) ? part[t] : 0;
  sd[t] = v;
  __syncthreads();
  for (int off = 1; off < 1024; off <<= 1) {
    int x = 0;
    if (t >= off) x = sd[t - off];
    __syncthreads();
    if (t >= off) sd[t] += x;
    __syncthreads();
  }
  if (t < nblk) part[t] = sd[t] - v;
}

__global__ void k_scan3(int* __restrict__ rp, const int* __restrict__ part,
                        int n, int E) {
  int t = threadIdx.x;
  int add = part[blockIdx.x];
  int base = blockIdx.x * 1024 + t * 4;
#pragma unroll
  for (int i = 0; i < 4; ++i)
    if (base + i < n) rp[base + i] += add;
  if (blockIdx.x == 0 && t == 0) rp[n] = E;
}

// -------------------------------------------- bucketed CSR: pass A scatter
// packed pair: (d & 511) << 23 | src   (src < 2^23)
__global__ __launch_bounds__(256) void kB_scat(const int* __restrict__ src,
                                               const int* __restrict__ dst,
                                               const int* __restrict__ off,
                                               unsigned int* __restrict__ pairs,
                                               int E, int nbuk) {
  __shared__ int cur[256];
  int tid = threadIdx.x;
  for (int i = tid; i < nbuk; i += 256)
    cur[i] = off[(size_t)i * NBLK + blockIdx.x];
  __syncthreads();
  int epb = (E + NBLK - 1) / NBLK;
  int e0 = blockIdx.x * epb;
  int e1 = min(E, e0 + epb);
  for (int e = e0 + tid; e < e1; e += 256) {
    int s = src[e];
    int d = dst[e];
    int p = atomicAdd(&cur[d >> NPB_SHIFT], 1);
    pairs[p] = ((unsigned)(d & (NPB - 1)) << 23) | (unsigned)s;
  }
}

// ---------------------------------------------- bucketed CSR: pass B build
__global__ __launch_bounds__(512) void kB_build(
    const unsigned int* __restrict__ pairs, const int* __restrict__ off,
    int* __restrict__ rp, int* __restrict__ col, int N, int nbuk, int E) {
  __shared__ int cnt[NPB];
  __shared__ int exc[NPB];
  __shared__ int colstage[CAP];
  int tid = threadIdx.x;
  int b = blockIdx.x;
  int eb = off[(size_t)b * NBLK];
  int ee = off[(size_t)(b + 1) * NBLK];
  int m = ee - eb;

  cnt[tid] = 0;
  __syncthreads();
  for (int i = eb + tid; i < ee; i += NPB) {
    int dl = (int)(pairs[i] >> 23);
    atomicAdd(&cnt[dl], 1);
  }
  __syncthreads();
  exc[tid] = cnt[tid];
  __syncthreads();
  for (int o = 1; o < NPB; o <<= 1) {
    int v = (tid >= o) ? exc[tid - o] : 0;
    __syncthreads();
    exc[tid] += v;
    __syncthreads();
  }
  int myexc = exc[tid] - cnt[tid];
  int node = b * NPB + tid;
  if (node < N) rp[node] = eb + myexc;
  if (b == nbuk - 1 && tid == 0) rp[N] = E;
  __syncthreads();
  cnt[tid] = myexc;  // reuse as cursor
  __syncthreads();
  if (m <= CAP) {
    for (int i = eb + tid; i < ee; i += NPB) {
      unsigned int pr = pairs[i];
      int dl = (int)(pr >> 23);
      int s = (int)(pr & 0x7fffffu);
      int p = atomicAdd(&cnt[dl], 1);
      colstage[p] = s;
    }
    __syncthreads();
    for (int i = tid; i < m; i += NPB) col[eb + i] = colstage[i];
  } else {
    for (int i = eb + tid; i < ee; i += NPB) {
      unsigned int pr = pairs[i];
      int dl = (int)(pr >> 23);
      int s = (int)(pr & 0x7fffffu);
      int p = atomicAdd(&cnt[dl], 1);
      col[eb + p] = s;
    }
  }
}

// ------------------------------------------------------- fused MFMA GEMM
// col-split: each block does 128 rows x 64 cols of BOTH mats -> acc 64 VGPR,
// 4 blocks/CU. Adjacent block pairs share rows (hb L2 reuse).
__global__ __launch_bounds__(256, 4) void k_gemm2(
    const unsigned short* __restrict__ hb, const unsigned short* __restrict__ WpS,
    const unsigned short* __restrict__ WpN, float* __restrict__ z,
    unsigned short* __restrict__ yb, int n) {
  const int l = threadIdx.x & 63;
  const int w = threadIdx.x >> 6;
  const int rb = blockIdx.x >> 1;
  const int cb = blockIdx.x & 1;  // column half: ct in [cb*4, cb*4+4)
  const int rowW = rb * 128 + w * 32;
  const int cl = l & 15;
  const int cg = l >> 4;

  bf16x8 A[2][4];
#pragma unroll
  for (int rt = 0; rt < 2; ++rt) {
    int row = rowW + rt * 16 + cl;
#pragma unroll
    for (int kf = 0; kf < 4; ++kf) {
      if (row < n)
        A[rt][kf] = *(const bf16x8*)(hb + (size_t)row * 128 + kf * 32 + cg * 8);
      else
        A[rt][kf] = (bf16x8){0, 0, 0, 0, 0, 0, 0, 0};
    }
  }

  f32x4 accS[2][4], accN[2][4];
#pragma unroll
  for (int rt = 0; rt < 2; ++rt)
#pragma unroll
    for (int ct = 0; ct < 4; ++ct) {
      accS[rt][ct] = (f32x4){0.f, 0.f, 0.f, 0.f};
      accN[rt][ct] = (f32x4){0.f, 0.f, 0.f, 0.f};
    }

#pragma unroll
  for (int ct = 0; ct < 4; ++ct) {
    int ctg = cb * 4 + ct;
    bf16x8 BS[4], BN[4];
#pragma unroll
    for (int kf = 0; kf < 4; ++kf) {
      BS[kf] = *(const bf16x8*)(WpS + ((ctg * 4 + kf) * 64 + l) * 8);
      BN[kf] = *(const bf16x8*)(WpN + ((ctg * 4 + kf) * 64 + l) * 8);
    }
#pragma unroll
    for (int rt = 0; rt < 2; ++rt)
#pragma unroll
      for (int kf = 0; kf < 4; ++kf) {
        accS[rt][ct] =
            __builtin_amdgcn_mfma_f32_16x16x32_bf16(A[rt][kf], BS[kf], accS[rt][ct], 0, 0, 0);
        accN[rt][ct] =
            __builtin_amdgcn_mfma_f32_16x16x32_bf16(A[rt][kf], BN[kf], accN[rt][ct], 0, 0, 0);
      }
  }

#pragma unroll
  for (int rt = 0; rt < 2; ++rt)
#pragma unroll
    for (int ct = 0; ct < 4; ++ct) {
      int colc = (cb * 4 + ct) * 16 + cl;
#pragma unroll
      for (int r = 0; r < 4; ++r) {
        int row = rowW + rt * 16 + cg * 4 + r;
        if (row < n) {
          z[(size_t)row * 128 + colc] = accS[rt][ct][r];
          yb[(size_t)row * 128 + colc] = f2bf(accN[rt][ct][r]);
        }
      }
    }
}

// ------------------------------------------------- aggregation (pull, fused)
// round-6 form: one wave per node, wave-uniform col index (scalar loads),
// 4B bf16-pair per lane, 8-deep gather unroll.
template <int OUTMODE>
__global__ __launch_bounds__(256, 8) void k_aggr2(
    const unsigned int* __restrict__ Y, const float* Z,
    const int* __restrict__ rp, const int* __restrict__ col,
    const float* __restrict__ bias, void* outp, int n) {
  int wid = (blockIdx.x * 256 + threadIdx.x) >> 6;
  int lane = threadIdx.x & 63;
  if (wid >= n) return;
  int s = rp[wid], e = rp[wid + 1];
  float ax = 0.f, ay = 0.f;
  int i = s;
  for (; i + 8 <= e; i += 8) {
    unsigned int v0 = Y[(size_t)col[i + 0] * 64 + lane];
    unsigned int v1 = Y[(size_t)col[i + 1] * 64 + lane];
    unsigned int v2 = Y[(size_t)col[i + 2] * 64 + lane];
    unsigned int v3 = Y[(size_t)col[i + 3] * 64 + lane];
    unsigned int v4 = Y[(size_t)col[i + 4] * 64 + lane];
    unsigned int v5 = Y[(size_t)col[i + 5] * 64 + lane];
    unsigned int v6 = Y[(size_t)col[i + 6] * 64 + lane];
    unsigned int v7 = Y[(size_t)col[i + 7] * 64 + lane];
    ax += bflo(v0) + bflo(v1) + bflo(v2) + bflo(v3) + bflo(v4) + bflo(v5) +
          bflo(v6) + bflo(v7);
    ay += bfhi(v0) + bfhi(v1) + bfhi(v2) + bfhi(v3) + bfhi(v4) + bfhi(v5) +
          bfhi(v6) + bfhi(v7);
  }
  for (; i + 4 <= e; i += 4) {
    unsigned int v0 = Y[(size_t)col[i + 0] * 64 + lane];
    unsigned int v1 = Y[(size_t)col[i + 1] * 64 + lane];
    unsigned int v2 = Y[(size_t)col[i + 2] * 64 + lane];
    unsigned int v3 = Y[(size_t)col[i + 3] * 64 + lane];
    ax += bflo(v0) + bflo(v1) + bflo(v2) + bflo(v3);
    ay += bfhi(v0) + bfhi(v1) + bfhi(v2) + bfhi(v3);
  }
  for (; i < e; ++i) {
    unsigned int v = Y[(size_t)col[i] * 64 + lane];
    ax += bflo(v);
    ay += bfhi(v);
  }
  int deg = e - s;
  float scale = 1.0f / (float)(deg > 1 ? deg : 1);
  float2 zv = ((const float2*)Z)[(size_t)wid * 64 + lane];
  float2 bb = ((const float2*)bias)[lane];
  float ox = zv.x + ax * scale + bb.x;
  float oy = zv.y + ay * scale + bb.y;
  if (OUTMODE == 1) {
    ox = fmaxf(ox, 0.f);
    oy = fmaxf(oy, 0.f);
    unsigned int packed = (unsigned int)f2bf(ox) | ((unsigned int)f2bf(oy) << 16);
    ((unsigned int*)outp)[(size_t)wid * 64 + lane] = packed;
  } else {
    ((float2*)outp)[(size_t)wid * 64 + lane] = make_float2(ox, oy);
  }
}

// ---------------------------------------------------------------- pooling
__global__ __launch_bounds__(256) void k_pool(const float* __restrict__ H2,
                                              const int* __restrict__ gids,
                                              float* __restrict__ gsum, int N) {
  int g = blockIdx.x / PCHUNK;
  int c = blockIdx.x % PCHUNK;
  int t = threadIdx.x;
  int s = lowerb(gids, N, g);
  int e = lowerb(gids, N, g + 1);
  int cnt = e - s;
  int per = (cnt + PCHUNK - 1) / PCHUNK;
  int rs = s + c * per;
  int re = rs + per < e ? rs + per : e;
  if (rs >= re) return;  // uniform per block
  int rslot = t >> 5;    // 0..7
  int d4 = t & 31;       // float4 index within row
  const float4* H4 = (const float4*)H2;
  float4 acc = make_float4(0.f, 0.f, 0.f, 0.f);
  for (int r = rs + rslot; r < re; r += 8) {
    float4 v = H4[(size_t)r * 32 + d4];
    acc.x += v.x; acc.y += v.y; acc.z += v.z; acc.w += v.w;
  }
  __shared__ float4 sacc[256];
  sacc[t] = acc;
  __syncthreads();
#pragma unroll
  for (int o = 4; o >= 1; o >>= 1) {
    if (rslot < o) {
      float4 a = sacc[t];
      float4 b = sacc[t + o * 32];
      a.x += b.x; a.y += b.y; a.z += b.z; a.w += b.w;
      sacc[t] = a;
    }
    __syncthreads();
  }
  if (t < 32) {
    float4 a = sacc[t];
    atomicAdd(&gsum[g * DID + t * 4 + 0], a.x);
    atomicAdd(&gsum[g * DID + t * 4 + 1], a.y);
    atomicAdd(&gsum[g * DID + t * 4 + 2], a.z);
    atomicAdd(&gsum[g * DID + t * 4 + 3], a.w);
  }
}

__global__ void k_head(const float* __restrict__ gsum,
                       const float* __restrict__ perm,
                       const float* __restrict__ Wc,
                       const float* __restrict__ bc,
                       const int* __restrict__ gids, float* __restrict__ out,
                       int N, int NG) {
  int t = threadIdx.x;
  if (t >= NG * NCLS) return;
  int g = t >> 3, c = t & 7;
  int cnt = lowerb(gids, N, g + 1) - lowerb(gids, N, g);
  float inv = 1.0f / (float)(cnt > 1 ? cnt : 1);
  float acc = bc[c];
#pragma unroll 4
  for (int k = 0; k < DID; ++k)
    acc += gsum[g * DID + k] * inv * Wc[k * NCLS + c];
#pragma unroll 4
  for (int k = 0; k < DID; ++k)
    acc += perm[g * DID + k] * Wc[(DID + k) * NCLS + c];
  out[g * NCLS + c] = acc;
}

// ---------------------------------------------------------------- launch
extern "C" void kernel_launch(void* const* d_in, const int* in_sizes, int n_in,
                              void* d_out, int out_size, void* d_ws,
                              size_t ws_size, hipStream_t stream) {
  const float* h = (const float*)d_in[0];
  const float* perm = (const float*)d_in[1];
  const int* src = (const int*)d_in[2];
  const int* dst = (const int*)d_in[3];
  const int* gids = (const int*)d_in[4];
  const float* W1s = (const float*)d_in[5];
  const float* W1n = (const float*)d_in[6];
  const float* b1 = (const float*)d_in[7];
  const float* W2s = (const float*)d_in[8];
  const float* W2n = (const float*)d_in[9];
  const float* b2 = (const float*)d_in[10];
  const float* Wc = (const float*)d_in[11];
  const float* bc = (const float*)d_in[12];
  float* out = (float*)d_out;

  const int N = in_sizes[0] / DID;
  const int E = in_sizes[2];
  const int NG = in_sizes[1] / DID;
  const int nbuk = (N + NPB - 1) >> NPB_SHIFT;
  const int nscan = nbuk * NBLK;

  char* w = (char*)d_ws;
  size_t off_ = 0;
  auto alloc = [&](size_t bytes) -> void* {
    off_ = (off_ + 511) & ~(size_t)511;
    void* p = w + off_;
    off_ += bytes;
    return p;
  };
  float* gsum = (float*)alloc((size_t)NG * DID * 4);
  int* hist = (int*)alloc((size_t)nscan * 4);
  int* boff = (int*)alloc((size_t)(nscan + 1) * 4);
  int* part = (int*)alloc(1024 * 4);
  int* rp = (int*)alloc((size_t)(N + 1) * 4);
  int* col = (int*)alloc((size_t)E * 4);
  unsigned int* pairs = (unsigned int*)alloc((size_t)E * 4);
  unsigned short* hb = (unsigned short*)alloc((size_t)N * DID * 2);
  unsigned short* yb = (unsigned short*)alloc((size_t)N * DID * 2);
  float* z = (float*)alloc((size_t)N * DID * 4);
  unsigned short* Wp1s = (unsigned short*)alloc(128 * 128 * 2);
  unsigned short* Wp1n = (unsigned short*)alloc(128 * 128 * 2);
  unsigned short* Wp2s = (unsigned short*)alloc(128 * 128 * 2);
  unsigned short* Wp2n = (unsigned short*)alloc(128 * 128 * 2);

  const int nchunk = (nscan + 1023) / 1024;
  const int ngb2 = ((N + 127) / 128) * 2;
  const int nagg = (N + 3) / 4;
  const int total8 = N * DID / 8;
  const int ncvt = (total8 + 255) / 256;

  // fused prep: h->bf16, weight pack, bucket hist, gsum zero
  k_prep<<<ncvt + 256 + NBLK + 1, 256, 0, stream>>>(
      h, hb, total8, ncvt, W1s, W1n, W2s, W2n, Wp1s, Wp1n, Wp2s, Wp2n, dst,
      hist, E, nbuk, gsum, NG * DID);

  // bucketed CSR by dst
  k_scan1<<<nchunk, 256, 0, stream>>>(hist, boff, part, nscan);
  k_scan2<<<1, 1024, 0, stream>>>(part, nchunk);
  k_scan3<<<nchunk, 256, 0, stream>>>(boff, part, nscan, E);
  kB_scat<<<NBLK, 256, 0, stream>>>(src, dst, boff, pairs, E, nbuk);
  kB_build<<<nbuk, NPB, 0, stream>>>(pairs, boff, rp, col, N, nbuk, E);

  // layer 1: z=h@W1s (f32), yb=h@W1n (bf16); aggr -> h1 bf16 (into hb)
  k_gemm2<<<ngb2, 256, 0, stream>>>(hb, Wp1s, Wp1n, z, yb, N);
  k_aggr2<1><<<nagg, 256, 0, stream>>>((const unsigned int*)yb, z, rp, col, b1,
                                       (void*)hb, N);

  // layer 2: z=h1@W2s, yb=h1@W2n; aggr -> h2 fp32 (in-place in z)
  k_gemm2<<<ngb2, 256, 0, stream>>>(hb, Wp2s, Wp2n, z, yb, N);
  k_aggr2<0><<<nagg, 256, 0, stream>>>((const unsigned int*)yb, z, rp, col, b2,
                                       (void*)z, N);

  // readout
  k_pool<<<NG * PCHUNK, 256, 0, stream>>>(z, gids, gsum, N);
  k_head<<<1, 512, 0, stream>>>(gsum, perm, Wc, bc, gids, out, N, NG);
}